// Round 11
// baseline (286.469 us; speedup 1.0000x reference)
//
#include <hip/hip_runtime.h>
#include <hip/hip_bf16.h>
#include <math.h>

// Problem dims
#define BB 16
#define NN 100
#define MAXNB 10
#define NBONDS 120
#define AF 82
#define BF 6
#define HH 300
#define BIN 11
#define DEPTH 3
#define KTOP 80

typedef __attribute__((ext_vector_type(8))) short short8;
typedef __attribute__((ext_vector_type(4))) float floatx4;

__device__ __forceinline__ unsigned short f2bf(float f) {
    unsigned int u = __float_as_uint(f);
    unsigned int r = (u + 0x7FFFu + ((u >> 16) & 1u)) >> 16;
    return (unsigned short)r;
}
__device__ __forceinline__ float bf2f(unsigned short h) {
    return __uint_as_float(((unsigned int)h) << 16);
}

// W-frag table offsets (in shorts), identical layout for hi and lo planes.
// HW panel order (slots 3..5): [W_nei_atom | W_self | W_U2a] (ld 900).
// U1A+U1B are STACKED into one kc=20 table at O_U1CAT (h' = [h|nl]@[U1A;U1B]).
#define O_WATOM 0        // kc=3
#define O_WNB   29184    // kc=1
#define O_U2B   38912    // kc=1
#define O_WNA   48640    // kc=10  panel 0
#define O_P1    145920   //        panel 1 = W_self
#define O_P2    243200   //        panel 2 = W_U2a
#define O_U1CAT 340480   // kc=20 stacked [U1A;U1B]  (spans old U1A+U1B slots)
#define O_WATT  535040
#define O_WPL   632320
#define O_WPG   729600

// ---------------------------------------------------------------------------
// Fused prep, FLAT grid (4733 blocks — no padded-out empty dispatches):
//   [0,114)    z0  W_atom (kc=3)        [114,152)  z1  W_nei_bond (kc=1)
//   [152,190)  z2  W_U2b (kc=1)         [190,3230) z3..z10 8x kc=10 slices
//   [3230,4070) input conv              [4070,4733) pair tables
//   (z=6,7 write interleaved into the kc=20 U1CAT table)
// ---------------------------------------------------------------------------
__global__ __launch_bounds__(256) void k_prep(
    const float* __restrict__ s0, const float* __restrict__ s1,
    const float* __restrict__ s2, const float* __restrict__ s3,
    const float* __restrict__ s4, const float* __restrict__ s5,
    const float* __restrict__ s6, const float* __restrict__ s7,
    const float* __restrict__ s8, const float* __restrict__ s9,
    const float* __restrict__ s10,
    unsigned short* __restrict__ WTh, unsigned short* __restrict__ WTl,
    const float* __restrict__ fatoms, const float* __restrict__ fbonds,
    unsigned short* __restrict__ fatomsbf, unsigned short* __restrict__ fbondsbf,
    const float* __restrict__ bin, unsigned short* __restrict__ BINBF,
    const float* __restrict__ Wbin0, const float* __restrict__ Wbin1,
    unsigned short* __restrict__ WBF0, unsigned short* __restrict__ WBF1)
{
    const int bx0 = blockIdx.x;
    int z, bxl;
    if (bx0 < 114)       { z = 0;  bxl = bx0; }
    else if (bx0 < 152)  { z = 1;  bxl = bx0 - 114; }
    else if (bx0 < 190)  { z = 2;  bxl = bx0 - 152; }
    else if (bx0 < 3230) { int t = bx0 - 190; z = 3 + t / 380; bxl = t % 380; }
    else if (bx0 < 4070) { z = 11; bxl = bx0 - 3230; }
    else                 { z = 12; bxl = bx0 - 4070; }

    if (z == 11) {
        int idx = bxl * 256 + threadIdx.x;
        if (idx < 1600 * 96) {
            int r = idx / 96, c = idx - r * 96;
            float f = (c < AF) ? fatoms[r * AF + c] : 0.f;
            unsigned short hb = f2bf(f);
            fatomsbf[r * 192 + c]      = hb;
            fatomsbf[r * 192 + 96 + c] = f2bf(f - bf2f(hb));
        } else {
            int i2 = idx - 1600 * 96;
            if (i2 < 1920 * 32) {
                int r = i2 / 32, c = i2 - r * 32;
                float f = (c < BF) ? fbonds[r * BF + c] : 0.f;
                unsigned short hb = f2bf(f);
                fbondsbf[r * 64 + c]      = hb;
                fbondsbf[r * 64 + 32 + c] = f2bf(f - bf2f(hb));
            }
        }
        return;
    }
    if (z == 12) {
        if (bxl < 625) {
            int p = bxl * 256 + threadIdx.x;
            if (p < BB * NN * NN) {
                const float* src = bin + (size_t)p * BIN;
                unsigned short tmp[16];
#pragma unroll
                for (int k = 0; k < BIN; k++) tmp[k] = f2bf(src[k]);
#pragma unroll
                for (int k = BIN; k < 16; k++) tmp[k] = 0;
                *(uint4*)(BINBF + (size_t)p * 16) = *(uint4*)tmp;
                *(uint4*)(BINBF + (size_t)p * 16 + 8) = *(uint4*)(tmp + 8);
            }
        } else if (bxl < 663) {
            int zb = bxl - 625;            // 0..37
            const float* src = (zb >= 19) ? Wbin1 : Wbin0;
            unsigned short* dst = (zb >= 19) ? WBF1 : WBF0;
            int idx = (zb % 19) * 256 + threadIdx.x;
            int jj = idx & 7;
            int koct = (idx >> 3) & 1;
            int n = (idx >> 4) & 15;
            int ch = idx >> 8;
            int k = koct * 8 + jj;
            int h = ch * 16 + n;
            float f = (k < BIN && h < 300) ? src[k * 300 + h] : 0.f;
            dst[idx] = f2bf(f);
        }
        return;
    }
    const float* src; int K, kc, off, u1base = -1;
    switch (z) {
        case 0:  src = s0;  K = AF;  kc = 3;  off = O_WATOM; break;
        case 1:  src = s1;  K = BF;  kc = 1;  off = O_WNB;   break;
        case 2:  src = s2;  K = BF;  kc = 1;  off = O_U2B;   break;
        case 3:  src = s3;  K = HH;  kc = 10; off = O_WNA;   break;
        case 4:  src = s4;  K = HH;  kc = 10; off = O_P1;    break;
        case 5:  src = s5;  K = HH;  kc = 10; off = O_P2;    break;
        case 6:  src = s6;  K = HH;  kc = 10; off = O_U1CAT; u1base = 0;  break;
        case 7:  src = s7;  K = HH;  kc = 10; off = O_U1CAT; u1base = 10; break;
        case 8:  src = s8;  K = HH;  kc = 10; off = O_WATT;  break;
        case 9:  src = s9;  K = HH;  kc = 10; off = O_WPL;   break;
        default: src = s10; K = HH;  kc = 10; off = O_WPG;   break;
    }
    const int lim = 9728 * kc;
    int i = bxl * 256 + threadIdx.x;
    if (i < lim) {
        int jj = i & 7;
        int lane = (i >> 3) & 63;
        int rem = i >> 9;
        int kci = rem % kc;
        int ct = rem / kc;
        int k = kci * 32 + (lane >> 4) * 8 + jj;
        int col = ct * 16 + (lane & 15);
        float f = (k < K && col < 300) ? src[k * 300 + col] : 0.f;
        unsigned short hb = f2bf(f);
        // u1cat: kc=20 table layout, this slice occupies kci band [u1base, u1base+10)
        int dsti = (u1base >= 0)
                 ? off + ct * 10240 + (kci + u1base) * 512 + lane * 8 + jj
                 : off + i;
        WTh[dsti] = hb;
        WTl[dsti] = f2bf(f - bf2f(hb));
    }
}

// ---------------------------------------------------------------------------
// Epilogue helper (compile-time-static indexing only).
// ---------------------------------------------------------------------------
__device__ __forceinline__ void gemm_epilogue(
    floatx4 acc, int ct, int m, int rq, int row0,
    float* __restrict__ C, int ldc, const float* __restrict__ bias,
    int act, unsigned short* __restrict__ Cbf, int gcolBase)
{
    const int col = ct * 16 + m;
    if (col >= 300) return;
    const float bv = bias ? bias[col] : 0.f;
    const int gcol = gcolBase + col;
#pragma unroll
    for (int r = 0; r < 4; r++) {
        const int grow = row0 + rq * 4 + r;
        float v = acc[r] + bv;
        if (act) v = fmaxf(v, 0.f);
        if (C) C[(size_t)grow * ldc + gcol] = v;
        if (Cbf) {
            unsigned short hb = f2bf(v);
            Cbf[(size_t)grow * 640 + col]       = hb;
            Cbf[(size_t)grow * 640 + 320 + col] = f2bf(v - bf2f(hb));
        }
    }
}

// ---------------------------------------------------------------------------
// bf16x3 MFMA GEMM core, 32-row tiles: each wave computes TWO 16-row tiles
// (rows m and m+16) with the SAME weight fragments — the weight stream (the
// L2-resident operand, ~40KB/wave) is amortized over 2x the MFMAs, and two
// independent acc chains interleave. KC is a template param so LDS is sized
// exactly (KC=10: 41.5KB -> 3 blocks/CU = 12 waves/CU).
// ---------------------------------------------------------------------------
template<int KC>
__device__ __forceinline__ void gemm_core32(
    const unsigned short* __restrict__ A, int lda, int M,
    const unsigned short* __restrict__ wthB, const unsigned short* __restrict__ wtlB,
    float* __restrict__ C, int ldc,
    const float* __restrict__ bias,
    int act, unsigned short* __restrict__ Cbf,
    int row0, int gcolBase)
{
    constexpr int sR = KC * 64 + 8;
    __shared__ unsigned short sa[32 * sR];
    if (row0 >= M) return;                       // block-uniform
    const int tid = threadIdx.x;
    const int lane = tid & 63;
    const int wid = tid >> 6;

    {
        const uint4* Ag = (const uint4*)A;
        uint4* sa4 = (uint4*)sa;
        constexpr int q4 = KC * 8;
        const int lda4 = lda >> 3;
        constexpr int sR4 = q4 + 1;
        for (int i = tid; i < 32 * q4; i += 256) {
            int r = i / q4, q = i - r * q4;
            sa4[r * sR4 + q] = Ag[(size_t)(row0 + r) * lda4 + q];
        }
    }
    __syncthreads();

    const int ct = blockIdx.y * 4 + wid;
    if (ct >= 19) return;

    const int m = lane & 15;
    const int rq = lane >> 4;
    const int koct8 = rq * 8;
    const unsigned short* wth = wthB + (size_t)ct * KC * 512;
    const unsigned short* wtl = wtlB + (size_t)ct * KC * 512;

    floatx4 acc0 = {0.f, 0.f, 0.f, 0.f};
    floatx4 acc1 = {0.f, 0.f, 0.f, 0.f};
    for (int kci = 0; kci < KC; kci++) {
        short8 ah0 = *(const short8*)(sa + m * sR + kci * 32 + koct8);
        short8 al0 = *(const short8*)(sa + m * sR + KC * 32 + kci * 32 + koct8);
        short8 ah1 = *(const short8*)(sa + (16 + m) * sR + kci * 32 + koct8);
        short8 al1 = *(const short8*)(sa + (16 + m) * sR + KC * 32 + kci * 32 + koct8);
        short8 wh = *(const short8*)(wth + (kci * 64 + lane) * 8);
        short8 wl = *(const short8*)(wtl + (kci * 64 + lane) * 8);
        acc0 = __builtin_amdgcn_mfma_f32_16x16x32_bf16(ah0, wl, acc0, 0, 0, 0);
        acc1 = __builtin_amdgcn_mfma_f32_16x16x32_bf16(ah1, wl, acc1, 0, 0, 0);
        acc0 = __builtin_amdgcn_mfma_f32_16x16x32_bf16(al0, wh, acc0, 0, 0, 0);
        acc1 = __builtin_amdgcn_mfma_f32_16x16x32_bf16(al1, wh, acc1, 0, 0, 0);
        acc0 = __builtin_amdgcn_mfma_f32_16x16x32_bf16(ah0, wh, acc0, 0, 0, 0);
        acc1 = __builtin_amdgcn_mfma_f32_16x16x32_bf16(ah1, wh, acc1, 0, 0, 0);
    }

    gemm_epilogue(acc0, ct, m, rq, row0,      C, ldc, bias, act, Cbf, gcolBase);
    gemm_epilogue(acc1, ct, m, rq, row0 + 16, C, ldc, bias, act, Cbf, gcolBase);
}

// Grid: (M/32, 5, nW) — same-row blocks land on one XCD.
__global__ __launch_bounds__(256) void k_gemm_mfma(
    const unsigned short* __restrict__ A, int lda, int M,
    const unsigned short* __restrict__ WTh, const unsigned short* __restrict__ WTl,
    int wtStride,
    float* __restrict__ C, int ldc,
    const float* __restrict__ bias,
    int act, unsigned short* __restrict__ Cbf)
{
    const int widx = blockIdx.z;
    gemm_core32<10>(A, lda, M,
              WTh + (size_t)widx * wtStride, WTl + (size_t)widx * wtStride,
              C, ldc, bias, act, Cbf,
              blockIdx.x * 32, widx * 300);
}

// ---------------------------------------------------------------------------
// k_gemm_u1: h' = relu([h|nl] @ [U1A;U1B] + b_U1) -> hbf_next (hi/lo).
// kc=20 concat GEMM: stages 16 rows from BOTH hbf(cur) and nlbf, planes
// interleaved [h_hi|nl_hi|h_lo|nl_lo] to match the kci 0..19 fragment order.
// (16-row: a 32-row kc=20 tile would need 82KB LDS -> 1 block/CU.)
// ---------------------------------------------------------------------------
__global__ __launch_bounds__(256) void k_gemm_u1(
    const unsigned short* __restrict__ Ah,   // hbf cur, row stride 640
    const unsigned short* __restrict__ An,   // nlbf, row stride 640
    const unsigned short* __restrict__ WTh, const unsigned short* __restrict__ WTl,
    const float* __restrict__ bias,
    unsigned short* __restrict__ Cbf)        // hbf next
{
    __shared__ unsigned short sa[16 * 1288];   // kc=20: 20*64+8 = 1288
    const int row0 = blockIdx.x * 16;
    if (row0 >= 1600) return;                  // block-uniform
    const int tid = threadIdx.x;
    const int lane = tid & 63;
    const int wid = tid >> 6;

    {
        const uint4* Ag = (const uint4*)Ah;
        const uint4* Ng = (const uint4*)An;
        uint4* sa4 = (uint4*)sa;
        for (int i = tid; i < 16 * 160; i += 256) {
            int r = i / 160, q = i - r * 160;
            const size_t rb = (size_t)(row0 + r) * 80;
            uint4 v;
            if (q < 40)       v = Ag[rb + q];            // h hi
            else if (q < 80)  v = Ng[rb + (q - 40)];     // nl hi
            else if (q < 120) v = Ag[rb + (q - 40)];     // h lo  (40..79)
            else              v = Ng[rb + (q - 80)];     // nl lo (40..79)
            sa4[r * 161 + q] = v;
        }
    }
    __syncthreads();

    const int ct = blockIdx.y * 4 + wid;
    if (ct >= 19) return;

    const int m = lane & 15;
    const int rq = lane >> 4;
    const int koct8 = rq * 8;
    const unsigned short* wth = WTh + (size_t)ct * 10240;
    const unsigned short* wtl = WTl + (size_t)ct * 10240;

    floatx4 acc = {0.f, 0.f, 0.f, 0.f};
    for (int kci = 0; kci < 20; kci++) {
        short8 ah = *(const short8*)(sa + m * 1288 + kci * 32 + koct8);
        short8 al = *(const short8*)(sa + m * 1288 + 640 + kci * 32 + koct8);
        short8 wh = *(const short8*)(wth + (kci * 64 + lane) * 8);
        short8 wl = *(const short8*)(wtl + (kci * 64 + lane) * 8);
        acc = __builtin_amdgcn_mfma_f32_16x16x32_bf16(ah, wl, acc, 0, 0, 0);
        acc = __builtin_amdgcn_mfma_f32_16x16x32_bf16(al, wh, acc, 0, 0, 0);
        acc = __builtin_amdgcn_mfma_f32_16x16x32_bf16(ah, wh, acc, 0, 0, 0);
    }

    const int col = ct * 16 + m;
    if (col < 300) {
        const float bv = bias[col];
#pragma unroll
        for (int r = 0; r < 4; r++) {
            const int grow = row0 + rq * 4 + r;
            float v = fmaxf(acc[r] + bv, 0.f);
            unsigned short hb = f2bf(v);
            Cbf[(size_t)grow * 640 + col]       = hb;
            Cbf[(size_t)grow * 640 + 320 + col] = f2bf(v - bf2f(hb));
        }
    }
}

// Fused opening GEMMs: z=0 -> h = relu(fatoms@W_atom) -> hbf (M=1600);
// z=1,2 -> FB = fbonds @ [W_nei_bond | W_U2b] -> f32 ld 600 (M=1920).
__global__ __launch_bounds__(256) void k_gemm_first(
    const unsigned short* __restrict__ fatomsbf,
    const unsigned short* __restrict__ fbondsbf,
    const unsigned short* __restrict__ WTh, const unsigned short* __restrict__ WTl,
    unsigned short* __restrict__ hbf, float* __restrict__ FBout)
{
    const int z = blockIdx.z;
    if (z == 0) {
        gemm_core32<3>(fatomsbf, 192, 1600,
                  WTh + O_WATOM, WTl + O_WATOM,
                  nullptr, 0, nullptr, 1, hbf,
                  blockIdx.x * 32, 0);
    } else {
        const int w = z - 1;
        gemm_core32<1>(fbondsbf, 64, 1920,
                  WTh + O_WNB + w * 9728, WTl + O_WNB + w * 9728,
                  FBout, 600, nullptr, 0, nullptr,
                  blockIdx.x * 32, w * 300);
    }
}

// ---------------------------------------------------------------------------
// k_neighbor v2: TLP split across tz (k 0-4 / 5-9), 2 bn/block, grid 800.
// HW is ld 900 (stride 225 float4): ha=cols 0-300, sf=300-600, hu=600-900.
// computeU1=0 (last depth iter): nl dead -> skip hu/fu loads + nlbf writes.
// XCD swizzle: batch = bx&15.
// ---------------------------------------------------------------------------
__global__ __launch_bounds__(320, 4) void k_neighbor(
    const float* __restrict__ HW, const float* __restrict__ FB,
    const int* __restrict__ atom_nb, const int* __restrict__ bond_nb,
    const float* __restrict__ mask_neis, const float* __restrict__ mask_atoms,
    const float* __restrict__ b_U2,
    unsigned short* __restrict__ localbf, unsigned short* __restrict__ nlbf,
    int computeU1)
{
    __shared__ int   sAn[2][MAXNB];
    __shared__ int   sBd[2][MAXNB];
    __shared__ float sM[2][MAXNB];
    __shared__ float pF[2][300];
    __shared__ float pN[2][300];
    const int tx = threadIdx.x;            // 0..79 (75 used)
    const int ty = threadIdx.y;            // bn within block: 0..1
    const int tz = threadIdx.z;            // k-half: 0..1
    const int bx = blockIdx.x;
    const int bn0 = ((bx & 15) * 50 + (bx >> 4)) * 2;
    const int flat = (tz * 2 + ty) * 80 + tx;

    if (flat < 20)       sAn[flat / 10][flat % 10] = atom_nb[(bn0 + flat / 10) * MAXNB + flat % 10];
    else if (flat < 40)  { int f = flat - 20; sBd[f / 10][f % 10] = bond_nb[(bn0 + f / 10) * MAXNB + f % 10]; }
    else if (flat < 60)  { int f = flat - 40; sM[f / 10][f % 10]  = mask_neis[(bn0 + f / 10) * MAXNB + f % 10]; }
    __syncthreads();

    const int bn = bn0 + ty;
    const int b = bn / NN;
    const int h4 = tx;
    const float4* HW4 = (const float4*)HW;
    const float4* FB4 = (const float4*)FB;

    float4 fnei = make_float4(0.f, 0.f, 0.f, 0.f);
    float4 nls  = fnei;
    if (tx < 75) {
        if (computeU1) {
            const float4 bu = ((const float4*)b_U2)[h4];
#pragma unroll
            for (int kk = 0; kk < 5; kk++) {
                const int k = tz * 5 + kk;
                const int an = sAn[ty][k];
                const int bd = sBd[ty][k];
                const float m = sM[ty][k];
                const float4* hr = HW4 + (size_t)(b * NN + an) * 225;
                const float4* fr = FB4 + (size_t)(b * NBONDS + bd) * 150;
                float4 ha = hr[h4];
                float4 hu = hr[150 + h4];     // U2a panel (cols 600-900)
                float4 fa = fr[h4];
                float4 fu = fr[75 + h4];
                fnei.x = fmaf(m, ha.x * fa.x, fnei.x);
                fnei.y = fmaf(m, ha.y * fa.y, fnei.y);
                fnei.z = fmaf(m, ha.z * fa.z, fnei.z);
                fnei.w = fmaf(m, ha.w * fa.w, fnei.w);
                float ux = hu.x + fu.x + bu.x;
                float uy = hu.y + fu.y + bu.y;
                float uz = hu.z + fu.z + bu.z;
                float uw = hu.w + fu.w + bu.w;
                nls.x = fmaf(m, fmaxf(ux, 0.f), nls.x);
                nls.y = fmaf(m, fmaxf(uy, 0.f), nls.y);
                nls.z = fmaf(m, fmaxf(uz, 0.f), nls.z);
                nls.w = fmaf(m, fmaxf(uw, 0.f), nls.w);
            }
        } else {
#pragma unroll
            for (int kk = 0; kk < 5; kk++) {
                const int k = tz * 5 + kk;
                const int an = sAn[ty][k];
                const int bd = sBd[ty][k];
                const float m = sM[ty][k];
                float4 ha = HW4[(size_t)(b * NN + an) * 225 + h4];
                float4 fa = FB4[(size_t)(b * NBONDS + bd) * 150 + h4];
                fnei.x = fmaf(m, ha.x * fa.x, fnei.x);
                fnei.y = fmaf(m, ha.y * fa.y, fnei.y);
                fnei.z = fmaf(m, ha.z * fa.z, fnei.z);
                fnei.w = fmaf(m, ha.w * fa.w, fnei.w);
            }
        }
        if (tz == 1) {
            ((float4*)pF[ty])[h4] = fnei;
            if (computeU1) ((float4*)pN[ty])[h4] = nls;
        }
    }
    __syncthreads();

    if (tx < 75 && tz == 0) {
        const float4 pf = ((const float4*)pF[ty])[h4];
        fnei.x += pf.x; fnei.y += pf.y; fnei.z += pf.z; fnei.w += pf.w;

        const float ma = mask_atoms[bn];
        const float4 sf = HW4[(size_t)bn * 225 + 75 + h4];   // W_self panel (cols 300-600)
        float lv[4];
        lv[0] = fnei.x * sf.x * ma; lv[1] = fnei.y * sf.y * ma;
        lv[2] = fnei.z * sf.z * ma; lv[3] = fnei.w * sf.w * ma;

        ushort4 lh, ll;
        unsigned short* lhp = (unsigned short*)&lh;
        unsigned short* llp = (unsigned short*)&ll;
#pragma unroll
        for (int c = 0; c < 4; c++) {
            unsigned short hb = f2bf(lv[c]);
            lhp[c] = hb; llp[c] = f2bf(lv[c] - bf2f(hb));
        }
        *(ushort4*)(localbf + (size_t)bn * 640 + h4 * 4)       = lh;
        *(ushort4*)(localbf + (size_t)bn * 640 + 320 + h4 * 4) = ll;

        if (computeU1) {
            const float4 pn = ((const float4*)pN[ty])[h4];
            float nv[4] = {nls.x + pn.x, nls.y + pn.y, nls.z + pn.z, nls.w + pn.w};
            ushort4 nh, nl2;
            unsigned short* nhp = (unsigned short*)&nh;
            unsigned short* nlp = (unsigned short*)&nl2;
#pragma unroll
            for (int c = 0; c < 4; c++) {
                unsigned short nb = f2bf(nv[c]);
                nhp[c] = nb; nlp[c] = f2bf(nv[c] - bf2f(nb));
            }
            *(ushort4*)(nlbf + (size_t)bn * 640 + h4 * 4)       = nh;
            *(ushort4*)(nlbf + (size_t)bn * 640 + 320 + h4 * 4) = nl2;
        }
    }
}

// ---------------------------------------------------------------------------
// k_pair: R6-proven version. Row-major LDS, stride 308 (2-way aliasing only
// — free per bank rules). liv reads are same-address broadcasts; ljv reads
// are 2-way. Transposed variant (R7) regressed: 8-way WRITE conflicts.
// Batch-major grid (XCD-pinned).
// ---------------------------------------------------------------------------
__global__ __launch_bounds__(256) void k_pair(
    const float* __restrict__ R, int ldr,
    const unsigned short* __restrict__ BINBF,
    const unsigned short* __restrict__ WBF,
    const float* __restrict__ bvec,
    const float* __restrict__ Wscore, const float* __restrict__ bscore,
    float* __restrict__ outp, int mode)
{
    __shared__ float sLi[16 * 308];
    __shared__ float sLj[16 * 308];

    const int b  = blockIdx.x;                 // XCD = b & 7
    const int i0 = blockIdx.y * 16;
    const int j0 = blockIdx.z * 16;
    const int tid = threadIdx.x;
    const int lane = tid & 63;
    const int wid = tid >> 6;

    for (int idx = tid; idx < 16 * 308; idx += 256) {
        int r = idx / 308;
        int c = idx - r * 308;
        float vi = 0.f, vj = 0.f;
        if (c < 300) {
            if (i0 + r < NN) vi = R[(size_t)(b * NN + i0 + r) * ldr + c] + bvec[c];
            if (j0 + r < NN) vj = R[(size_t)(b * NN + j0 + r) * ldr + c];
        }
        sLi[idx] = vi;
        sLj[idx] = vj;
    }

    const int m = lane & 15;
    const int koct = lane >> 4;
    short8 afrag[4];
#pragma unroll
    for (int g = 0; g < 4; g++) {
        int ii = i0 + wid * 4 + g; if (ii > NN - 1) ii = NN - 1;
        int jj2 = j0 + m;          if (jj2 > NN - 1) jj2 = NN - 1;
        const size_t pidx = (size_t)((b * NN + ii) * NN + jj2);
        afrag[g] = *(const short8*)(BINBF + pidx * 16 + (koct & 1) * 8);
        if (koct >= 2) afrag[g] = short8{0,0,0,0,0,0,0,0};
    }
    __syncthreads();

    const int n = lane & 15;
    const int rquad = lane >> 4;
    const floatx4 zero = {0.f, 0.f, 0.f, 0.f};
    float su[4][4];
#pragma unroll
    for (int g = 0; g < 4; g++)
#pragma unroll
        for (int r = 0; r < 4; r++) su[g][r] = 0.f;

    for (int ch = 0; ch < 19; ch++) {
        const int h0 = ch * 16;
        short8 bfrag = {0,0,0,0,0,0,0,0};
        if (lane < 32)
            bfrag = *(const short8*)(WBF + ch * 256 + (n * 2 + koct) * 8);
        float wsv = 0.f;
        if (h0 + n < 300) wsv = Wscore[h0 + n];
#pragma unroll
        for (int g = 0; g < 4; g++) {
            floatx4 P = __builtin_amdgcn_mfma_f32_16x16x32_bf16(
                afrag[g], bfrag, zero, 0, 0, 0);
            const float liv = sLi[(wid * 4 + g) * 308 + h0 + n];
#pragma unroll
            for (int r = 0; r < 4; r++) {
                const float ljv = sLj[(rquad * 4 + r) * 308 + h0 + n];
                float u = P[r] + liv + ljv;
                su[g][r] = fmaf(fmaxf(u, 0.f), wsv, su[g][r]);
            }
        }
    }

    const float bs = bscore[0];
#pragma unroll
    for (int g = 0; g < 4; g++) {
#pragma unroll
        for (int r = 0; r < 4; r++) {
            float v = su[g][r];
            v += __shfl_xor(v, 1);
            v += __shfl_xor(v, 2);
            v += __shfl_xor(v, 4);
            v += __shfl_xor(v, 8);
            if (n == 0) {
                const int i = i0 + wid * 4 + g;
                const int j = j0 + rquad * 4 + r;
                if (i < NN && j < NN) {
                    float s = v + bs;
                    outp[(size_t)(b * NN + i) * NN + j] =
                        (mode == 0) ? (1.f / (1.f + expf(-s))) : s;
                }
            }
        }
    }
}

// ---------------------------------------------------------------------------
// k_ctx: LPG[b,i,:] = sum_j att[b,i,j] * LL[b,j,600:900] + LL[b,i,300:600]
// (associativity: ctx@W_pg == att@(local@W_pg); W_pg folded into LL GEMM).
// 4 i-rows/block; batch-XCD swizzle; all-f32.
// ---------------------------------------------------------------------------
__global__ __launch_bounds__(320, 2) void k_ctx(
    const float* __restrict__ att, const float* __restrict__ LL,
    float* __restrict__ LPG)
{
    const int bx = blockIdx.x;
    const int b = bx & 15;
    const int i0 = (bx >> 4) * 4;
    const int tid = threadIdx.x;
    __shared__ float sa[4 * NN];
    for (int idx = tid; idx < 4 * NN; idx += 320) {
        int ii = idx / NN, j = idx - ii * NN;
        sa[idx] = att[(size_t)(b * NN + i0 + ii) * NN + j];
    }
    __syncthreads();
    if (tid < HH) {
        float acc0 = 0.f, acc1 = 0.f, acc2 = 0.f, acc3 = 0.f;
#pragma unroll 4
        for (int j = 0; j < NN; j++) {
            const float lv = LL[(size_t)(b * NN + j) * 900 + 600 + tid];
            acc0 = fmaf(sa[j], lv, acc0);
            acc1 = fmaf(sa[NN + j], lv, acc1);
            acc2 = fmaf(sa[2 * NN + j], lv, acc2);
            acc3 = fmaf(sa[3 * NN + j], lv, acc3);
        }
        float vals[4] = {acc0, acc1, acc2, acc3};
#pragma unroll
        for (int k = 0; k < 4; k++) {
            LPG[(size_t)(b * NN + i0 + k) * 300 + tid] =
                vals[k] + LL[(size_t)(b * NN + i0 + k) * 900 + 300 + tid];
        }
    }
}

// ---------------------------------------------------------------------------
// Top-K with adaptive early stop: radix passes refine the threshold prefix;
// stop as soon as the selected bin's count hb <= TCAP-KTOP (then candidates
// u > T number <= (KTOP-1) + hb < TCAP — provable bound). Candidates are
// ranked by (value desc, index asc); exact-T elements fill by index order —
// identical tie semantics to the full 4-pass version (= jax.lax.top_k).
// Expected 2 passes on random data; worst case = old behavior.
// ---------------------------------------------------------------------------
#define TCAP 512
__global__ __launch_bounds__(1024) void k_topk(
    const float* __restrict__ scores, float* __restrict__ topk_out)
{
    const int b = blockIdx.x;
    const int tid = threadIdx.x;
    const int wid = tid >> 6;
    const int lane = tid & 63;
    const float* sc = scores + (size_t)b * (NN * NN);

    __shared__ unsigned int skey[NN * NN];
    __shared__ unsigned int whist[16 * 256];
    __shared__ unsigned int hist[256];
    __shared__ unsigned int candU[TCAP];
    __shared__ int candI[TCAP];
    __shared__ int cntG;
    __shared__ int curMin;
    __shared__ unsigned int sh_pref, sh_mask;
    __shared__ int sh_kRem;
    __shared__ int sh_last;
    __shared__ int sh_hb;

    for (int idx = tid; idx < NN * NN; idx += 1024) {
        unsigned int u = __float_as_uint(sc[idx]);
        u = (u & 0x80000000u) ? ~u : (u | 0x80000000u);
        skey[idx] = u;
    }
    if (tid == 0) {
        sh_pref = 0u; sh_mask = 0u; sh_kRem = KTOP; cntG = 0; sh_last = -1;
        sh_hb = 0x7fffffff;
    }
    __syncthreads();

    for (int pass = 0; pass < 4; pass++) {
        const int shift = 24 - 8 * pass;
        unsigned int* wh = whist + (wid << 8);
        wh[lane] = 0u; wh[lane + 64] = 0u; wh[lane + 128] = 0u; wh[lane + 192] = 0u;
        __syncthreads();
        const unsigned int pref = sh_pref, mask = sh_mask;
        for (int idx = tid; idx < NN * NN; idx += 1024) {
            unsigned int u = skey[idx];
            if ((u & mask) == pref)
                atomicAdd(&wh[(u >> shift) & 255u], 1u);
        }
        __syncthreads();
        if (tid < 256) {
            unsigned int s = 0u;
#pragma unroll
            for (int w = 0; w < 16; w++) s += whist[(w << 8) | tid];
            hist[tid] = s;
        }
        __syncthreads();
        if (wid == 0) {
            unsigned int h0 = hist[lane * 4 + 0];
            unsigned int h1 = hist[lane * 4 + 1];
            unsigned int h2 = hist[lane * 4 + 2];
            unsigned int h3 = hist[lane * 4 + 3];
            unsigned int own = h0 + h1 + h2 + h3;
            unsigned int suf = own;
#pragma unroll
            for (int off = 1; off < 64; off <<= 1) {
                unsigned int v = __shfl_down(suf, off);
                if (lane + off < 64) suf += v;
            }
            const int k = sh_kRem;
            const unsigned int above = suf - own;
            if (above < (unsigned int)k && suf >= (unsigned int)k) {
                unsigned int c = above, hb; int bsel;
                c += h3;
                if ((int)c >= k) { bsel = lane * 4 + 3; hb = h3; }
                else { c += h2;
                    if ((int)c >= k) { bsel = lane * 4 + 2; hb = h2; }
                    else { c += h1;
                        if ((int)c >= k) { bsel = lane * 4 + 1; hb = h1; }
                        else { c += h0; bsel = lane * 4; hb = h0; } } }
                sh_kRem = k - (int)(c - hb);
                sh_pref = pref | ((unsigned int)bsel << shift);
                sh_mask = mask | (0xFFu << shift);
                sh_hb = (int)hb;
            }
        }
        __syncthreads();
        if (sh_hb <= TCAP - KTOP) break;   // uniform read post-barrier
    }
    const unsigned int T = sh_pref;

    for (int idx = tid; idx < NN * NN; idx += 1024) {
        unsigned int u = skey[idx];
        if (u > T) {
            int pos = atomicAdd(&cntG, 1);
            if (pos < TCAP) { candU[pos] = u; candI[pos] = idx; }
        }
    }
    __syncthreads();
    const int cg = (cntG < TCAP) ? cntG : TCAP;
    const int needE = KTOP - cg;

    for (int e = 0; e < needE; e++) {
        if (tid == 0) curMin = 0x7fffffff;
        __syncthreads();
        const int last = sh_last;
        for (int idx = tid; idx < NN * NN; idx += 1024) {
            if (skey[idx] == T && idx > last)
                atomicMin(&curMin, idx);
        }
        __syncthreads();
        if (tid == 0) {
            candU[cg + e] = T;
            candI[cg + e] = curMin;
            sh_last = curMin;
        }
        __syncthreads();
    }

    const int nc = (cg < KTOP) ? KTOP : cg;
    if (tid < nc) {
        const unsigned int mu = candU[tid];
        const int mi = candI[tid];
        int rank = 0;
        for (int o = 0; o < nc; o++) {
            unsigned int ou = candU[o];
            int oi = candI[o];
            if (ou > mu || (ou == mu && oi < mi)) rank++;
        }
        if (rank < KTOP)
            topk_out[b * KTOP + rank] = (float)mi;
    }
}

// ---------------------------------------------------------------------------
extern "C" void kernel_launch(void* const* d_in, const int* in_sizes, int n_in,
                              void* d_out, int out_size, void* d_ws, size_t ws_size,
                              hipStream_t stream) {
    const float* fatoms       = (const float*)d_in[0];
    const float* fbonds       = (const float*)d_in[1];
    const int*   atom_nb      = (const int*)d_in[2];
    const int*   bond_nb      = (const int*)d_in[3];
    const float* binary_feats = (const float*)d_in[6];
    const float* mask_neis    = (const float*)d_in[7];
    const float* mask_atoms   = (const float*)d_in[8];
    const float* W_atom       = (const float*)d_in[10];
    const float* W_nei_atom   = (const float*)d_in[11];
    const float* W_nei_bond   = (const float*)d_in[12];
    const float* W_self       = (const float*)d_in[13];
    const float* W_U2         = (const float*)d_in[14];
    const float* b_U2         = (const float*)d_in[15];
    const float* W_U1         = (const float*)d_in[16];
    const float* b_U1         = (const float*)d_in[17];
    const float* W_att_local  = (const float*)d_in[18];
    const float* W_att_bin    = (const float*)d_in[19];
    const float* b_att        = (const float*)d_in[20];
    const float* W_att_score  = (const float*)d_in[21];
    const float* b_att_score  = (const float*)d_in[22];
    const float* W_pl         = (const float*)d_in[23];
    const float* W_pg         = (const float*)d_in[24];
    const float* W_pb         = (const float*)d_in[25];
    const float* b_p          = (const float*)d_in[26];
    const float* W_out        = (const float*)d_in[27];
    const float* b_out        = (const float*)d_in[28];

    float* ws = (float*)d_ws;
    // f32 slots
    float* HW  = ws;                         // 1,440,000 f (1600 x 900)
    float* FB  = HW + 1440000;               // 1,152,000 f (1920 x 600)
    float* LL  = FB + 1152000;               // 1,440,000 f (1600 x 900)
    float* LPG = LL + 1440000;               //   480,000 f (1600 x 300)
    float* att = LPG + 480000;               //   160,000 f
    // shorts region (no aliasing; ws is 268 MB, we use ~36 MB)
    unsigned short* S0       = (unsigned short*)(ws + 4672000);
    unsigned short* hbf      = S0;                         // 1,024,000
    unsigned short* hbf2     = S0 + 1024000;               // 1,024,000
    unsigned short* nlbf     = S0 + 2048000;               // 1,024,000
    unsigned short* localbf  = S0 + 3072000;               // 1,024,000
    unsigned short* WTh      = S0 + 4096000;               //   826,880
    unsigned short* WTl      = S0 + 4922880;               //   826,880
    unsigned short* BINBF    = S0 + 5749760;               // 2,560,000
    unsigned short* WBF_att  = S0 + 8309760;               //     4,864
    unsigned short* WBF_fin  = S0 + 8314624;               //     4,864
    unsigned short* fatomsbf = S0 + 8319488;               //   307,200
    unsigned short* fbondsbf = S0 + 8626688;               //   122,880

    float* out = (float*)d_out;
    float* topk_out = out + (size_t)BB * NN * NN;

    // fused prep (flat 4733-block grid): 11 weight tables (z=6,7 -> kc=20
    // U1CAT) + input conv + pair tables
    k_prep<<<dim3(4733), 256, 0, stream>>>(
        W_atom, W_nei_bond, W_U2 + 300 * 300, W_nei_atom, W_self, W_U2,
        W_U1, W_U1 + 300 * 300, W_att_local, W_pl, W_pg, WTh, WTl,
        fatoms, fbonds, fatomsbf, fbondsbf,
        binary_feats, BINBF, W_att_bin, W_pb, WBF_att, WBF_fin);

    // fused opening GEMMs: h -> hbf (z=0, M=1600); FB (z=1,2, M=1920)
    k_gemm_first<<<dim3(60, 5, 3), 256, 0, stream>>>(
        fatomsbf, fbondsbf, WTh, WTl, hbf, FB);

    unsigned short* hb[2] = {hbf, hbf2};
    int cur = 0;
    for (int d = 0; d < DEPTH; d++) {
        // HW = h @ [WNA | WSELF | (U2A)] -> f32 ld 900 (U1A folded into u1 GEMM)
        int nW = (d == DEPTH - 1) ? 2 : 3;
        k_gemm_mfma<<<dim3(50, 5, nW), 256, 0, stream>>>(
            hb[cur], 640, 1600, WTh + O_WNA, WTl + O_WNA, 97280,
            HW, 900, nullptr, 0, nullptr);
        // neighbor aggregate -> localbf (+nlbf when d<2); batch-XCD swizzled
        k_neighbor<<<dim3(800), dim3(80, 2, 2), 0, stream>>>(
            HW, FB, atom_nb, bond_nb, mask_neis, mask_atoms, b_U2,
            localbf, nlbf, (d < DEPTH - 1) ? 1 : 0);
        if (d < DEPTH - 1) {
            // h' = relu([h|nl] @ [U1A;U1B] + b_U1) -> ping-pong hbf
            k_gemm_u1<<<dim3(100, 5, 1), 256, 0, stream>>>(
                hb[cur], nlbf, WTh + O_U1CAT, WTl + O_U1CAT, b_U1, hb[cur ^ 1]);
            cur ^= 1;
        }
    }

    // LL = local @ [W_att_local | W_pl | W_pg] -> f32 ld 900
    k_gemm_mfma<<<dim3(50, 5, 3), 256, 0, stream>>>(
        localbf, 640, 1600, WTh + O_WATT, WTl + O_WATT, 97280,
        LL, 900, nullptr, 0, nullptr);

    // att[b,i,j] — pair kernel, batch-major grid (XCD-pinned)
    k_pair<<<dim3(16, 7, 7), 256, 0, stream>>>(
        LL, 900, BINBF, WBF_att, b_att, W_att_score, b_att_score,
        att, 0);

    // LPG = att @ LL[:,600:900] + LL[:,300:600] -> f32 ld 300
    k_ctx<<<dim3(BB * 25), 320, 0, stream>>>(att, LL, LPG);

    // pair scores — pair kernel, batch-major grid (XCD-pinned)
    k_pair<<<dim3(16, 7, 7), 256, 0, stream>>>(
        LPG, 300, BINBF, WBF_fin, b_p, W_out, b_out,
        out, 1);

    // top-k indices per batch (as float values)
    k_topk<<<dim3(BB), 1024, 0, stream>>>(out, topk_out);
}

// Round 12
// 283.683 us; speedup vs baseline: 1.0098x; 1.0098x over previous
//
#include <hip/hip_runtime.h>
#include <hip/hip_bf16.h>
#include <math.h>

// Problem dims
#define BB 16
#define NN 100
#define MAXNB 10
#define NBONDS 120
#define AF 82
#define BF 6
#define HH 300
#define BIN 11
#define DEPTH 3
#define KTOP 80

typedef __attribute__((ext_vector_type(8))) short short8;
typedef __attribute__((ext_vector_type(4))) float floatx4;

__device__ __forceinline__ unsigned short f2bf(float f) {
    unsigned int u = __float_as_uint(f);
    unsigned int r = (u + 0x7FFFu + ((u >> 16) & 1u)) >> 16;
    return (unsigned short)r;
}
__device__ __forceinline__ float bf2f(unsigned short h) {
    return __uint_as_float(((unsigned int)h) << 16);
}

// W-frag table offsets (in shorts), identical layout for hi and lo planes.
// HW panel order (slots 3..5): [W_nei_atom | W_self | W_U2a] (ld 900).
// U1A+U1B are STACKED into one kc=20 table at O_U1CAT (h' = [h|nl]@[U1A;U1B]).
#define O_WATOM 0        // kc=3
#define O_WNB   29184    // kc=1
#define O_U2B   38912    // kc=1
#define O_WNA   48640    // kc=10  panel 0
#define O_P1    145920   //        panel 1 = W_self
#define O_P2    243200   //        panel 2 = W_U2a
#define O_U1CAT 340480   // kc=20 stacked [U1A;U1B]  (spans old U1A+U1B slots)
#define O_WATT  535040
#define O_WPL   632320
#define O_WPG   729600

// ---------------------------------------------------------------------------
// Fused prep, FLAT grid (4733 blocks — no padded-out empty dispatches):
//   [0,114)    z0  W_atom (kc=3)        [114,152)  z1  W_nei_bond (kc=1)
//   [152,190)  z2  W_U2b (kc=1)         [190,3230) z3..z10 8x kc=10 slices
//   [3230,4070) input conv              [4070,4733) pair tables
//   (z=6,7 write interleaved into the kc=20 U1CAT table)
// ---------------------------------------------------------------------------
__global__ __launch_bounds__(256) void k_prep(
    const float* __restrict__ s0, const float* __restrict__ s1,
    const float* __restrict__ s2, const float* __restrict__ s3,
    const float* __restrict__ s4, const float* __restrict__ s5,
    const float* __restrict__ s6, const float* __restrict__ s7,
    const float* __restrict__ s8, const float* __restrict__ s9,
    const float* __restrict__ s10,
    unsigned short* __restrict__ WTh, unsigned short* __restrict__ WTl,
    const float* __restrict__ fatoms, const float* __restrict__ fbonds,
    unsigned short* __restrict__ fatomsbf, unsigned short* __restrict__ fbondsbf,
    const float* __restrict__ bin, unsigned short* __restrict__ BINBF,
    const float* __restrict__ Wbin0, const float* __restrict__ Wbin1,
    unsigned short* __restrict__ WBF0, unsigned short* __restrict__ WBF1)
{
    const int bx0 = blockIdx.x;
    int z, bxl;
    if (bx0 < 114)       { z = 0;  bxl = bx0; }
    else if (bx0 < 152)  { z = 1;  bxl = bx0 - 114; }
    else if (bx0 < 190)  { z = 2;  bxl = bx0 - 152; }
    else if (bx0 < 3230) { int t = bx0 - 190; z = 3 + t / 380; bxl = t % 380; }
    else if (bx0 < 4070) { z = 11; bxl = bx0 - 3230; }
    else                 { z = 12; bxl = bx0 - 4070; }

    if (z == 11) {
        int idx = bxl * 256 + threadIdx.x;
        if (idx < 1600 * 96) {
            int r = idx / 96, c = idx - r * 96;
            float f = (c < AF) ? fatoms[r * AF + c] : 0.f;
            unsigned short hb = f2bf(f);
            fatomsbf[r * 192 + c]      = hb;
            fatomsbf[r * 192 + 96 + c] = f2bf(f - bf2f(hb));
        } else {
            int i2 = idx - 1600 * 96;
            if (i2 < 1920 * 32) {
                int r = i2 / 32, c = i2 - r * 32;
                float f = (c < BF) ? fbonds[r * BF + c] : 0.f;
                unsigned short hb = f2bf(f);
                fbondsbf[r * 64 + c]      = hb;
                fbondsbf[r * 64 + 32 + c] = f2bf(f - bf2f(hb));
            }
        }
        return;
    }
    if (z == 12) {
        if (bxl < 625) {
            int p = bxl * 256 + threadIdx.x;
            if (p < BB * NN * NN) {
                const float* src = bin + (size_t)p * BIN;
                unsigned short tmp[16];
#pragma unroll
                for (int k = 0; k < BIN; k++) tmp[k] = f2bf(src[k]);
#pragma unroll
                for (int k = BIN; k < 16; k++) tmp[k] = 0;
                *(uint4*)(BINBF + (size_t)p * 16) = *(uint4*)tmp;
                *(uint4*)(BINBF + (size_t)p * 16 + 8) = *(uint4*)(tmp + 8);
            }
        } else if (bxl < 663) {
            int zb = bxl - 625;            // 0..37
            const float* src = (zb >= 19) ? Wbin1 : Wbin0;
            unsigned short* dst = (zb >= 19) ? WBF1 : WBF0;
            int idx = (zb % 19) * 256 + threadIdx.x;
            int jj = idx & 7;
            int koct = (idx >> 3) & 1;
            int n = (idx >> 4) & 15;
            int ch = idx >> 8;
            int k = koct * 8 + jj;
            int h = ch * 16 + n;
            float f = (k < BIN && h < 300) ? src[k * 300 + h] : 0.f;
            dst[idx] = f2bf(f);
        }
        return;
    }
    const float* src; int K, kc, off, u1base = -1;
    switch (z) {
        case 0:  src = s0;  K = AF;  kc = 3;  off = O_WATOM; break;
        case 1:  src = s1;  K = BF;  kc = 1;  off = O_WNB;   break;
        case 2:  src = s2;  K = BF;  kc = 1;  off = O_U2B;   break;
        case 3:  src = s3;  K = HH;  kc = 10; off = O_WNA;   break;
        case 4:  src = s4;  K = HH;  kc = 10; off = O_P1;    break;
        case 5:  src = s5;  K = HH;  kc = 10; off = O_P2;    break;
        case 6:  src = s6;  K = HH;  kc = 10; off = O_U1CAT; u1base = 0;  break;
        case 7:  src = s7;  K = HH;  kc = 10; off = O_U1CAT; u1base = 10; break;
        case 8:  src = s8;  K = HH;  kc = 10; off = O_WATT;  break;
        case 9:  src = s9;  K = HH;  kc = 10; off = O_WPL;   break;
        default: src = s10; K = HH;  kc = 10; off = O_WPG;   break;
    }
    const int lim = 9728 * kc;
    int i = bxl * 256 + threadIdx.x;
    if (i < lim) {
        int jj = i & 7;
        int lane = (i >> 3) & 63;
        int rem = i >> 9;
        int kci = rem % kc;
        int ct = rem / kc;
        int k = kci * 32 + (lane >> 4) * 8 + jj;
        int col = ct * 16 + (lane & 15);
        float f = (k < K && col < 300) ? src[k * 300 + col] : 0.f;
        unsigned short hb = f2bf(f);
        // u1cat: kc=20 table layout, this slice occupies kci band [u1base, u1base+10)
        int dsti = (u1base >= 0)
                 ? off + ct * 10240 + (kci + u1base) * 512 + lane * 8 + jj
                 : off + i;
        WTh[dsti] = hb;
        WTl[dsti] = f2bf(f - bf2f(hb));
    }
}

// ---------------------------------------------------------------------------
// bf16x3 MFMA GEMM core. Per k-chunk: acc += ah*wl + al*wh + ah*wh.
// (R9-proven 16-row version; both wider variants — 2-ct R4/R5 and 32-row
// R10/R11 — measured ~3% and ~1% slower: at M=1600 more concurrent blocks
// beat per-wave operand amortization.)
// ---------------------------------------------------------------------------
__device__ __forceinline__ void gemm_core(
    const unsigned short* __restrict__ A, int lda, int kc, int M,
    const unsigned short* __restrict__ wthB, const unsigned short* __restrict__ wtlB,
    float* __restrict__ C, int ldc,
    const float* __restrict__ bias,
    int act, unsigned short* __restrict__ Cbf,
    int row0, int gcolBase)
{
    __shared__ unsigned short sa[16 * 648];
    if (row0 >= M) return;                       // block-uniform
    const int tid = threadIdx.x;
    const int lane = tid & 63;
    const int wid = tid >> 6;
    const int sR = kc * 64 + 8;

    {
        const uint4* Ag = (const uint4*)A;
        uint4* sa4 = (uint4*)sa;
        const int q4 = kc * 8;
        const int lda4 = lda >> 3;
        const int sR4 = q4 + 1;
        for (int i = tid; i < 16 * q4; i += 256) {
            int r = i / q4, q = i - r * q4;
            sa4[r * sR4 + q] = Ag[(size_t)(row0 + r) * lda4 + q];
        }
    }
    __syncthreads();

    const int ct = blockIdx.y * 4 + wid;
    if (ct >= 19) return;

    const int m = lane & 15;
    const int rq = lane >> 4;
    const int koct8 = rq * 8;
    const unsigned short* wth = wthB + (size_t)ct * kc * 512;
    const unsigned short* wtl = wtlB + (size_t)ct * kc * 512;

    floatx4 acc = {0.f, 0.f, 0.f, 0.f};
    for (int kci = 0; kci < kc; kci++) {
        short8 ah = *(const short8*)(sa + m * sR + kci * 32 + koct8);
        short8 al = *(const short8*)(sa + m * sR + kc * 32 + kci * 32 + koct8);
        short8 wh = *(const short8*)(wth + (kci * 64 + lane) * 8);
        short8 wl = *(const short8*)(wtl + (kci * 64 + lane) * 8);
        acc = __builtin_amdgcn_mfma_f32_16x16x32_bf16(ah, wl, acc, 0, 0, 0);
        acc = __builtin_amdgcn_mfma_f32_16x16x32_bf16(al, wh, acc, 0, 0, 0);
        acc = __builtin_amdgcn_mfma_f32_16x16x32_bf16(ah, wh, acc, 0, 0, 0);
    }

    const int col = ct * 16 + m;
    if (col < 300) {
        const float bv = bias ? bias[col] : 0.f;
        const int gcol = gcolBase + col;
#pragma unroll
        for (int r = 0; r < 4; r++) {
            const int grow = row0 + rq * 4 + r;
            float v = acc[r] + bv;
            if (act) v = fmaxf(v, 0.f);
            if (C) C[(size_t)grow * ldc + gcol] = v;
            if (Cbf) {
                unsigned short hb = f2bf(v);
                Cbf[(size_t)grow * 640 + col]       = hb;
                Cbf[(size_t)grow * 640 + 320 + col] = f2bf(v - bf2f(hb));
            }
        }
    }
}

// Grid: (rowTiles, 5, nW) — same-row blocks land on one XCD.
__global__ __launch_bounds__(256) void k_gemm_mfma(
    const unsigned short* __restrict__ A, int lda, int kc, int M,
    const unsigned short* __restrict__ WTh, const unsigned short* __restrict__ WTl,
    int wtStride,
    float* __restrict__ C, int ldc,
    const float* __restrict__ bias,
    int act, unsigned short* __restrict__ Cbf)
{
    const int widx = blockIdx.z;
    gemm_core(A, lda, kc, M,
              WTh + (size_t)widx * wtStride, WTl + (size_t)widx * wtStride,
              C, ldc, bias, act, Cbf,
              blockIdx.x * 16, widx * 300);
}

// ---------------------------------------------------------------------------
// k_gemm_u1: h' = relu([h|nl] @ [U1A;U1B] + b_U1) -> hbf_next (hi/lo).
// kc=20 concat GEMM: stages 16 rows from BOTH hbf(cur) and nlbf, planes
// interleaved [h_hi|nl_hi|h_lo|nl_lo] to match the kci 0..19 fragment order.
// ---------------------------------------------------------------------------
__global__ __launch_bounds__(256) void k_gemm_u1(
    const unsigned short* __restrict__ Ah,   // hbf cur, row stride 640
    const unsigned short* __restrict__ An,   // nlbf, row stride 640
    const unsigned short* __restrict__ WTh, const unsigned short* __restrict__ WTl,
    const float* __restrict__ bias,
    unsigned short* __restrict__ Cbf)        // hbf next
{
    __shared__ unsigned short sa[16 * 1288];   // kc=20: 20*64+8 = 1288
    const int row0 = blockIdx.x * 16;
    if (row0 >= 1600) return;                  // block-uniform
    const int tid = threadIdx.x;
    const int lane = tid & 63;
    const int wid = tid >> 6;

    {
        const uint4* Ag = (const uint4*)Ah;
        const uint4* Ng = (const uint4*)An;
        uint4* sa4 = (uint4*)sa;
        for (int i = tid; i < 16 * 160; i += 256) {
            int r = i / 160, q = i - r * 160;
            const size_t rb = (size_t)(row0 + r) * 80;
            uint4 v;
            if (q < 40)       v = Ag[rb + q];            // h hi
            else if (q < 80)  v = Ng[rb + (q - 40)];     // nl hi
            else if (q < 120) v = Ag[rb + (q - 40)];     // h lo  (40..79)
            else              v = Ng[rb + (q - 80)];     // nl lo (40..79)
            sa4[r * 161 + q] = v;
        }
    }
    __syncthreads();

    const int ct = blockIdx.y * 4 + wid;
    if (ct >= 19) return;

    const int m = lane & 15;
    const int rq = lane >> 4;
    const int koct8 = rq * 8;
    const unsigned short* wth = WTh + (size_t)ct * 10240;
    const unsigned short* wtl = WTl + (size_t)ct * 10240;

    floatx4 acc = {0.f, 0.f, 0.f, 0.f};
    for (int kci = 0; kci < 20; kci++) {
        short8 ah = *(const short8*)(sa + m * 1288 + kci * 32 + koct8);
        short8 al = *(const short8*)(sa + m * 1288 + 640 + kci * 32 + koct8);
        short8 wh = *(const short8*)(wth + (kci * 64 + lane) * 8);
        short8 wl = *(const short8*)(wtl + (kci * 64 + lane) * 8);
        acc = __builtin_amdgcn_mfma_f32_16x16x32_bf16(ah, wl, acc, 0, 0, 0);
        acc = __builtin_amdgcn_mfma_f32_16x16x32_bf16(al, wh, acc, 0, 0, 0);
        acc = __builtin_amdgcn_mfma_f32_16x16x32_bf16(ah, wh, acc, 0, 0, 0);
    }

    const int col = ct * 16 + m;
    if (col < 300) {
        const float bv = bias[col];
#pragma unroll
        for (int r = 0; r < 4; r++) {
            const int grow = row0 + rq * 4 + r;
            float v = fmaxf(acc[r] + bv, 0.f);
            unsigned short hb = f2bf(v);
            Cbf[(size_t)grow * 640 + col]       = hb;
            Cbf[(size_t)grow * 640 + 320 + col] = f2bf(v - bf2f(hb));
        }
    }
}

// Fused opening GEMMs: z=0 -> h = relu(fatoms@W_atom) -> hbf;
// z=1,2 -> FB = fbonds @ [W_nei_bond | W_U2b] -> f32 ld 600.
__global__ __launch_bounds__(256) void k_gemm_first(
    const unsigned short* __restrict__ fatomsbf,
    const unsigned short* __restrict__ fbondsbf,
    const unsigned short* __restrict__ WTh, const unsigned short* __restrict__ WTl,
    unsigned short* __restrict__ hbf, float* __restrict__ FBout)
{
    const int z = blockIdx.z;
    if (z == 0) {
        gemm_core(fatomsbf, 192, 3, 1600,
                  WTh + O_WATOM, WTl + O_WATOM,
                  nullptr, 0, nullptr, 1, hbf,
                  blockIdx.x * 16, 0);
    } else {
        const int w = z - 1;
        gemm_core(fbondsbf, 64, 1, 1920,
                  WTh + O_WNB + w * 9728, WTl + O_WNB + w * 9728,
                  FBout, 600, nullptr, 0, nullptr,
                  blockIdx.x * 16, w * 300);
    }
}

// ---------------------------------------------------------------------------
// k_neighbor v2: TLP split across tz (k 0-4 / 5-9), 2 bn/block, grid 800.
// HW is ld 900 (stride 225 float4): ha=cols 0-300, sf=300-600, hu=600-900.
// computeU1=0 (last depth iter): nl dead -> skip hu/fu loads + nlbf writes.
// XCD swizzle: batch = bx&15.
// ---------------------------------------------------------------------------
__global__ __launch_bounds__(320, 4) void k_neighbor(
    const float* __restrict__ HW, const float* __restrict__ FB,
    const int* __restrict__ atom_nb, const int* __restrict__ bond_nb,
    const float* __restrict__ mask_neis, const float* __restrict__ mask_atoms,
    const float* __restrict__ b_U2,
    unsigned short* __restrict__ localbf, unsigned short* __restrict__ nlbf,
    int computeU1)
{
    __shared__ int   sAn[2][MAXNB];
    __shared__ int   sBd[2][MAXNB];
    __shared__ float sM[2][MAXNB];
    __shared__ float pF[2][300];
    __shared__ float pN[2][300];
    const int tx = threadIdx.x;            // 0..79 (75 used)
    const int ty = threadIdx.y;            // bn within block: 0..1
    const int tz = threadIdx.z;            // k-half: 0..1
    const int bx = blockIdx.x;
    const int bn0 = ((bx & 15) * 50 + (bx >> 4)) * 2;
    const int flat = (tz * 2 + ty) * 80 + tx;

    if (flat < 20)       sAn[flat / 10][flat % 10] = atom_nb[(bn0 + flat / 10) * MAXNB + flat % 10];
    else if (flat < 40)  { int f = flat - 20; sBd[f / 10][f % 10] = bond_nb[(bn0 + f / 10) * MAXNB + f % 10]; }
    else if (flat < 60)  { int f = flat - 40; sM[f / 10][f % 10]  = mask_neis[(bn0 + f / 10) * MAXNB + f % 10]; }
    __syncthreads();

    const int bn = bn0 + ty;
    const int b = bn / NN;
    const int h4 = tx;
    const float4* HW4 = (const float4*)HW;
    const float4* FB4 = (const float4*)FB;

    float4 fnei = make_float4(0.f, 0.f, 0.f, 0.f);
    float4 nls  = fnei;
    if (tx < 75) {
        if (computeU1) {
            const float4 bu = ((const float4*)b_U2)[h4];
#pragma unroll
            for (int kk = 0; kk < 5; kk++) {
                const int k = tz * 5 + kk;
                const int an = sAn[ty][k];
                const int bd = sBd[ty][k];
                const float m = sM[ty][k];
                const float4* hr = HW4 + (size_t)(b * NN + an) * 225;
                const float4* fr = FB4 + (size_t)(b * NBONDS + bd) * 150;
                float4 ha = hr[h4];
                float4 hu = hr[150 + h4];     // U2a panel (cols 600-900)
                float4 fa = fr[h4];
                float4 fu = fr[75 + h4];
                fnei.x = fmaf(m, ha.x * fa.x, fnei.x);
                fnei.y = fmaf(m, ha.y * fa.y, fnei.y);
                fnei.z = fmaf(m, ha.z * fa.z, fnei.z);
                fnei.w = fmaf(m, ha.w * fa.w, fnei.w);
                float ux = hu.x + fu.x + bu.x;
                float uy = hu.y + fu.y + bu.y;
                float uz = hu.z + fu.z + bu.z;
                float uw = hu.w + fu.w + bu.w;
                nls.x = fmaf(m, fmaxf(ux, 0.f), nls.x);
                nls.y = fmaf(m, fmaxf(uy, 0.f), nls.y);
                nls.z = fmaf(m, fmaxf(uz, 0.f), nls.z);
                nls.w = fmaf(m, fmaxf(uw, 0.f), nls.w);
            }
        } else {
#pragma unroll
            for (int kk = 0; kk < 5; kk++) {
                const int k = tz * 5 + kk;
                const int an = sAn[ty][k];
                const int bd = sBd[ty][k];
                const float m = sM[ty][k];
                float4 ha = HW4[(size_t)(b * NN + an) * 225 + h4];
                float4 fa = FB4[(size_t)(b * NBONDS + bd) * 150 + h4];
                fnei.x = fmaf(m, ha.x * fa.x, fnei.x);
                fnei.y = fmaf(m, ha.y * fa.y, fnei.y);
                fnei.z = fmaf(m, ha.z * fa.z, fnei.z);
                fnei.w = fmaf(m, ha.w * fa.w, fnei.w);
            }
        }
        if (tz == 1) {
            ((float4*)pF[ty])[h4] = fnei;
            if (computeU1) ((float4*)pN[ty])[h4] = nls;
        }
    }
    __syncthreads();

    if (tx < 75 && tz == 0) {
        const float4 pf = ((const float4*)pF[ty])[h4];
        fnei.x += pf.x; fnei.y += pf.y; fnei.z += pf.z; fnei.w += pf.w;

        const float ma = mask_atoms[bn];
        const float4 sf = HW4[(size_t)bn * 225 + 75 + h4];   // W_self panel (cols 300-600)
        float lv[4];
        lv[0] = fnei.x * sf.x * ma; lv[1] = fnei.y * sf.y * ma;
        lv[2] = fnei.z * sf.z * ma; lv[3] = fnei.w * sf.w * ma;

        ushort4 lh, ll;
        unsigned short* lhp = (unsigned short*)&lh;
        unsigned short* llp = (unsigned short*)&ll;
#pragma unroll
        for (int c = 0; c < 4; c++) {
            unsigned short hb = f2bf(lv[c]);
            lhp[c] = hb; llp[c] = f2bf(lv[c] - bf2f(hb));
        }
        *(ushort4*)(localbf + (size_t)bn * 640 + h4 * 4)       = lh;
        *(ushort4*)(localbf + (size_t)bn * 640 + 320 + h4 * 4) = ll;

        if (computeU1) {
            const float4 pn = ((const float4*)pN[ty])[h4];
            float nv[4] = {nls.x + pn.x, nls.y + pn.y, nls.z + pn.z, nls.w + pn.w};
            ushort4 nh, nl2;
            unsigned short* nhp = (unsigned short*)&nh;
            unsigned short* nlp = (unsigned short*)&nl2;
#pragma unroll
            for (int c = 0; c < 4; c++) {
                unsigned short nb = f2bf(nv[c]);
                nhp[c] = nb; nlp[c] = f2bf(nv[c] - bf2f(nb));
            }
            *(ushort4*)(nlbf + (size_t)bn * 640 + h4 * 4)       = nh;
            *(ushort4*)(nlbf + (size_t)bn * 640 + 320 + h4 * 4) = nl2;
        }
    }
}

// ---------------------------------------------------------------------------
// k_pair: R6-proven version. Row-major LDS, stride 308 (2-way aliasing only
// — free per bank rules). liv reads are same-address broadcasts; ljv reads
// are 2-way. Transposed variant (R7) regressed: 8-way WRITE conflicts.
// Batch-major grid (XCD-pinned).
// ---------------------------------------------------------------------------
__global__ __launch_bounds__(256) void k_pair(
    const float* __restrict__ R, int ldr,
    const unsigned short* __restrict__ BINBF,
    const unsigned short* __restrict__ WBF,
    const float* __restrict__ bvec,
    const float* __restrict__ Wscore, const float* __restrict__ bscore,
    float* __restrict__ outp, int mode)
{
    __shared__ float sLi[16 * 308];
    __shared__ float sLj[16 * 308];

    const int b  = blockIdx.x;                 // XCD = b & 7
    const int i0 = blockIdx.y * 16;
    const int j0 = blockIdx.z * 16;
    const int tid = threadIdx.x;
    const int lane = tid & 63;
    const int wid = tid >> 6;

    for (int idx = tid; idx < 16 * 308; idx += 256) {
        int r = idx / 308;
        int c = idx - r * 308;
        float vi = 0.f, vj = 0.f;
        if (c < 300) {
            if (i0 + r < NN) vi = R[(size_t)(b * NN + i0 + r) * ldr + c] + bvec[c];
            if (j0 + r < NN) vj = R[(size_t)(b * NN + j0 + r) * ldr + c];
        }
        sLi[idx] = vi;
        sLj[idx] = vj;
    }

    const int m = lane & 15;
    const int koct = lane >> 4;
    short8 afrag[4];
#pragma unroll
    for (int g = 0; g < 4; g++) {
        int ii = i0 + wid * 4 + g; if (ii > NN - 1) ii = NN - 1;
        int jj2 = j0 + m;          if (jj2 > NN - 1) jj2 = NN - 1;
        const size_t pidx = (size_t)((b * NN + ii) * NN + jj2);
        afrag[g] = *(const short8*)(BINBF + pidx * 16 + (koct & 1) * 8);
        if (koct >= 2) afrag[g] = short8{0,0,0,0,0,0,0,0};
    }
    __syncthreads();

    const int n = lane & 15;
    const int rquad = lane >> 4;
    const floatx4 zero = {0.f, 0.f, 0.f, 0.f};
    float su[4][4];
#pragma unroll
    for (int g = 0; g < 4; g++)
#pragma unroll
        for (int r = 0; r < 4; r++) su[g][r] = 0.f;

    for (int ch = 0; ch < 19; ch++) {
        const int h0 = ch * 16;
        short8 bfrag = {0,0,0,0,0,0,0,0};
        if (lane < 32)
            bfrag = *(const short8*)(WBF + ch * 256 + (n * 2 + koct) * 8);
        float wsv = 0.f;
        if (h0 + n < 300) wsv = Wscore[h0 + n];
#pragma unroll
        for (int g = 0; g < 4; g++) {
            floatx4 P = __builtin_amdgcn_mfma_f32_16x16x32_bf16(
                afrag[g], bfrag, zero, 0, 0, 0);
            const float liv = sLi[(wid * 4 + g) * 308 + h0 + n];
#pragma unroll
            for (int r = 0; r < 4; r++) {
                const float ljv = sLj[(rquad * 4 + r) * 308 + h0 + n];
                float u = P[r] + liv + ljv;
                su[g][r] = fmaf(fmaxf(u, 0.f), wsv, su[g][r]);
            }
        }
    }

    const float bs = bscore[0];
#pragma unroll
    for (int g = 0; g < 4; g++) {
#pragma unroll
        for (int r = 0; r < 4; r++) {
            float v = su[g][r];
            v += __shfl_xor(v, 1);
            v += __shfl_xor(v, 2);
            v += __shfl_xor(v, 4);
            v += __shfl_xor(v, 8);
            if (n == 0) {
                const int i = i0 + wid * 4 + g;
                const int j = j0 + rquad * 4 + r;
                if (i < NN && j < NN) {
                    float s = v + bs;
                    outp[(size_t)(b * NN + i) * NN + j] =
                        (mode == 0) ? (1.f / (1.f + expf(-s))) : s;
                }
            }
        }
    }
}

// ---------------------------------------------------------------------------
// k_ctx: LPG[b,i,:] = sum_j att[b,i,j] * LL[b,j,600:900] + LL[b,i,300:600]
// (associativity: ctx@W_pg == att@(local@W_pg); W_pg folded into LL GEMM).
// 4 i-rows/block; batch-XCD swizzle; all-f32.
// ---------------------------------------------------------------------------
__global__ __launch_bounds__(320, 2) void k_ctx(
    const float* __restrict__ att, const float* __restrict__ LL,
    float* __restrict__ LPG)
{
    const int bx = blockIdx.x;
    const int b = bx & 15;
    const int i0 = (bx >> 4) * 4;
    const int tid = threadIdx.x;
    __shared__ float sa[4 * NN];
    for (int idx = tid; idx < 4 * NN; idx += 320) {
        int ii = idx / NN, j = idx - ii * NN;
        sa[idx] = att[(size_t)(b * NN + i0 + ii) * NN + j];
    }
    __syncthreads();
    if (tid < HH) {
        float acc0 = 0.f, acc1 = 0.f, acc2 = 0.f, acc3 = 0.f;
#pragma unroll 4
        for (int j = 0; j < NN; j++) {
            const float lv = LL[(size_t)(b * NN + j) * 900 + 600 + tid];
            acc0 = fmaf(sa[j], lv, acc0);
            acc1 = fmaf(sa[NN + j], lv, acc1);
            acc2 = fmaf(sa[2 * NN + j], lv, acc2);
            acc3 = fmaf(sa[3 * NN + j], lv, acc3);
        }
        float vals[4] = {acc0, acc1, acc2, acc3};
#pragma unroll
        for (int k = 0; k < 4; k++) {
            LPG[(size_t)(b * NN + i0 + k) * 300 + tid] =
                vals[k] + LL[(size_t)(b * NN + i0 + k) * 900 + 300 + tid];
        }
    }
}

// ---------------------------------------------------------------------------
// Top-K with adaptive early stop: radix passes refine the threshold prefix;
// stop as soon as the selected bin's count hb <= TCAP-KTOP (then candidates
// u > T number <= (KTOP-1) + hb < TCAP — provable bound). Candidates are
// ranked by (value desc, index asc); exact-T elements fill by index order —
// identical tie semantics to the full 4-pass version (= jax.lax.top_k).
// Expected 2 passes on random data; worst case = old behavior.
// ---------------------------------------------------------------------------
#define TCAP 512
__global__ __launch_bounds__(1024) void k_topk(
    const float* __restrict__ scores, float* __restrict__ topk_out)
{
    const int b = blockIdx.x;
    const int tid = threadIdx.x;
    const int wid = tid >> 6;
    const int lane = tid & 63;
    const float* sc = scores + (size_t)b * (NN * NN);

    __shared__ unsigned int skey[NN * NN];
    __shared__ unsigned int whist[16 * 256];
    __shared__ unsigned int hist[256];
    __shared__ unsigned int candU[TCAP];
    __shared__ int candI[TCAP];
    __shared__ int cntG;
    __shared__ int curMin;
    __shared__ unsigned int sh_pref, sh_mask;
    __shared__ int sh_kRem;
    __shared__ int sh_last;
    __shared__ int sh_hb;

    for (int idx = tid; idx < NN * NN; idx += 1024) {
        unsigned int u = __float_as_uint(sc[idx]);
        u = (u & 0x80000000u) ? ~u : (u | 0x80000000u);
        skey[idx] = u;
    }
    if (tid == 0) {
        sh_pref = 0u; sh_mask = 0u; sh_kRem = KTOP; cntG = 0; sh_last = -1;
        sh_hb = 0x7fffffff;
    }
    __syncthreads();

    for (int pass = 0; pass < 4; pass++) {
        const int shift = 24 - 8 * pass;
        unsigned int* wh = whist + (wid << 8);
        wh[lane] = 0u; wh[lane + 64] = 0u; wh[lane + 128] = 0u; wh[lane + 192] = 0u;
        __syncthreads();
        const unsigned int pref = sh_pref, mask = sh_mask;
        for (int idx = tid; idx < NN * NN; idx += 1024) {
            unsigned int u = skey[idx];
            if ((u & mask) == pref)
                atomicAdd(&wh[(u >> shift) & 255u], 1u);
        }
        __syncthreads();
        if (tid < 256) {
            unsigned int s = 0u;
#pragma unroll
            for (int w = 0; w < 16; w++) s += whist[(w << 8) | tid];
            hist[tid] = s;
        }
        __syncthreads();
        if (wid == 0) {
            unsigned int h0 = hist[lane * 4 + 0];
            unsigned int h1 = hist[lane * 4 + 1];
            unsigned int h2 = hist[lane * 4 + 2];
            unsigned int h3 = hist[lane * 4 + 3];
            unsigned int own = h0 + h1 + h2 + h3;
            unsigned int suf = own;
#pragma unroll
            for (int off = 1; off < 64; off <<= 1) {
                unsigned int v = __shfl_down(suf, off);
                if (lane + off < 64) suf += v;
            }
            const int k = sh_kRem;
            const unsigned int above = suf - own;
            if (above < (unsigned int)k && suf >= (unsigned int)k) {
                unsigned int c = above, hb; int bsel;
                c += h3;
                if ((int)c >= k) { bsel = lane * 4 + 3; hb = h3; }
                else { c += h2;
                    if ((int)c >= k) { bsel = lane * 4 + 2; hb = h2; }
                    else { c += h1;
                        if ((int)c >= k) { bsel = lane * 4 + 1; hb = h1; }
                        else { c += h0; bsel = lane * 4; hb = h0; } } }
                sh_kRem = k - (int)(c - hb);
                sh_pref = pref | ((unsigned int)bsel << shift);
                sh_mask = mask | (0xFFu << shift);
                sh_hb = (int)hb;
            }
        }
        __syncthreads();
        if (sh_hb <= TCAP - KTOP) break;   // uniform read post-barrier
    }
    const unsigned int T = sh_pref;

    for (int idx = tid; idx < NN * NN; idx += 1024) {
        unsigned int u = skey[idx];
        if (u > T) {
            int pos = atomicAdd(&cntG, 1);
            if (pos < TCAP) { candU[pos] = u; candI[pos] = idx; }
        }
    }
    __syncthreads();
    const int cg = (cntG < TCAP) ? cntG : TCAP;
    const int needE = KTOP - cg;

    for (int e = 0; e < needE; e++) {
        if (tid == 0) curMin = 0x7fffffff;
        __syncthreads();
        const int last = sh_last;
        for (int idx = tid; idx < NN * NN; idx += 1024) {
            if (skey[idx] == T && idx > last)
                atomicMin(&curMin, idx);
        }
        __syncthreads();
        if (tid == 0) {
            candU[cg + e] = T;
            candI[cg + e] = curMin;
            sh_last = curMin;
        }
        __syncthreads();
    }

    const int nc = (cg < KTOP) ? KTOP : cg;
    if (tid < nc) {
        const unsigned int mu = candU[tid];
        const int mi = candI[tid];
        int rank = 0;
        for (int o = 0; o < nc; o++) {
            unsigned int ou = candU[o];
            int oi = candI[o];
            if (ou > mu || (ou == mu && oi < mi)) rank++;
        }
        if (rank < KTOP)
            topk_out[b * KTOP + rank] = (float)mi;
    }
}

// ---------------------------------------------------------------------------
extern "C" void kernel_launch(void* const* d_in, const int* in_sizes, int n_in,
                              void* d_out, int out_size, void* d_ws, size_t ws_size,
                              hipStream_t stream) {
    const float* fatoms       = (const float*)d_in[0];
    const float* fbonds       = (const float*)d_in[1];
    const int*   atom_nb      = (const int*)d_in[2];
    const int*   bond_nb      = (const int*)d_in[3];
    const float* binary_feats = (const float*)d_in[6];
    const float* mask_neis    = (const float*)d_in[7];
    const float* mask_atoms   = (const float*)d_in[8];
    const float* W_atom       = (const float*)d_in[10];
    const float* W_nei_atom   = (const float*)d_in[11];
    const float* W_nei_bond   = (const float*)d_in[12];
    const float* W_self       = (const float*)d_in[13];
    const float* W_U2         = (const float*)d_in[14];
    const float* b_U2         = (const float*)d_in[15];
    const float* W_U1         = (const float*)d_in[16];
    const float* b_U1         = (const float*)d_in[17];
    const float* W_att_local  = (const float*)d_in[18];
    const float* W_att_bin    = (const float*)d_in[19];
    const float* b_att        = (const float*)d_in[20];
    const float* W_att_score  = (const float*)d_in[21];
    const float* b_att_score  = (const float*)d_in[22];
    const float* W_pl         = (const float*)d_in[23];
    const float* W_pg         = (const float*)d_in[24];
    const float* W_pb         = (const float*)d_in[25];
    const float* b_p          = (const float*)d_in[26];
    const float* W_out        = (const float*)d_in[27];
    const float* b_out        = (const float*)d_in[28];

    float* ws = (float*)d_ws;
    // f32 slots
    float* HW  = ws;                         // 1,440,000 f (1600 x 900)
    float* FB  = HW + 1440000;               // 1,152,000 f (1920 x 600)
    float* LL  = FB + 1152000;               // 1,440,000 f (1600 x 900)
    float* LPG = LL + 1440000;               //   480,000 f (1600 x 300)
    float* att = LPG + 480000;               //   160,000 f
    // shorts region (no aliasing; ws is 268 MB, we use ~36 MB)
    unsigned short* S0       = (unsigned short*)(ws + 4672000);
    unsigned short* hbf      = S0;                         // 1,024,000
    unsigned short* hbf2     = S0 + 1024000;               // 1,024,000
    unsigned short* nlbf     = S0 + 2048000;               // 1,024,000
    unsigned short* localbf  = S0 + 3072000;               // 1,024,000
    unsigned short* WTh      = S0 + 4096000;               //   826,880
    unsigned short* WTl      = S0 + 4922880;               //   826,880
    unsigned short* BINBF    = S0 + 5749760;               // 2,560,000
    unsigned short* WBF_att  = S0 + 8309760;               //     4,864
    unsigned short* WBF_fin  = S0 + 8314624;               //     4,864
    unsigned short* fatomsbf = S0 + 8319488;               //   307,200
    unsigned short* fbondsbf = S0 + 8626688;               //   122,880

    float* out = (float*)d_out;
    float* topk_out = out + (size_t)BB * NN * NN;

    // fused prep (flat 4733-block grid): 11 weight tables (z=6,7 -> kc=20
    // U1CAT) + input conv + pair tables
    k_prep<<<dim3(4733), 256, 0, stream>>>(
        W_atom, W_nei_bond, W_U2 + 300 * 300, W_nei_atom, W_self, W_U2,
        W_U1, W_U1 + 300 * 300, W_att_local, W_pl, W_pg, WTh, WTl,
        fatoms, fbonds, fatomsbf, fbondsbf,
        binary_feats, BINBF, W_att_bin, W_pb, WBF_att, WBF_fin);

    // fused opening GEMMs: h -> hbf (z=0); FB (z=1,2)
    k_gemm_first<<<dim3(120, 5, 3), 256, 0, stream>>>(
        fatomsbf, fbondsbf, WTh, WTl, hbf, FB);

    unsigned short* hb[2] = {hbf, hbf2};
    int cur = 0;
    for (int d = 0; d < DEPTH; d++) {
        // HW = h @ [WNA | WSELF | (U2A)] -> f32 ld 900 (U1A folded into u1 GEMM)
        int nW = (d == DEPTH - 1) ? 2 : 3;
        k_gemm_mfma<<<dim3(104, 5, nW), 256, 0, stream>>>(
            hb[cur], 640, 10, 1600, WTh + O_WNA, WTl + O_WNA, 97280,
            HW, 900, nullptr, 0, nullptr);
        // neighbor aggregate -> localbf (+nlbf when d<2); batch-XCD swizzled
        k_neighbor<<<dim3(800), dim3(80, 2, 2), 0, stream>>>(
            HW, FB, atom_nb, bond_nb, mask_neis, mask_atoms, b_U2,
            localbf, nlbf, (d < DEPTH - 1) ? 1 : 0);
        if (d < DEPTH - 1) {
            // h' = relu([h|nl] @ [U1A;U1B] + b_U1) -> ping-pong hbf
            k_gemm_u1<<<dim3(100, 5, 1), 256, 0, stream>>>(
                hb[cur], nlbf, WTh + O_U1CAT, WTl + O_U1CAT, b_U1, hb[cur ^ 1]);
            cur ^= 1;
        }
    }

    // LL = local @ [W_att_local | W_pl | W_pg] -> f32 ld 900
    k_gemm_mfma<<<dim3(104, 5, 3), 256, 0, stream>>>(
        localbf, 640, 10, 1600, WTh + O_WATT, WTl + O_WATT, 97280,
        LL, 900, nullptr, 0, nullptr);

    // att[b,i,j] — pair kernel, batch-major grid (XCD-pinned)
    k_pair<<<dim3(16, 7, 7), 256, 0, stream>>>(
        LL, 900, BINBF, WBF_att, b_att, W_att_score, b_att_score,
        att, 0);

    // LPG = att @ LL[:,600:900] + LL[:,300:600] -> f32 ld 300
    k_ctx<<<dim3(BB * 25), 320, 0, stream>>>(att, LL, LPG);

    // pair scores — pair kernel, batch-major grid (XCD-pinned)
    k_pair<<<dim3(16, 7, 7), 256, 0, stream>>>(
        LPG, 300, BINBF, WBF_fin, b_p, W_out, b_out,
        out, 1);

    // top-k indices per batch (as float values)
    k_topk<<<dim3(BB), 1024, 0, stream>>>(out, topk_out);
}